// Round 5
// baseline (752.255 us; speedup 1.0000x reference)
//
#include <hip/hip_runtime.h>
#include <hip/hip_bf16.h>

typedef __hip_bfloat16 bf16;

#define ROWS 204800
#define N_INV (1.0f / 204800.0f)
#define NB 800          // grid size; co-residency: 4 blocks/CU * 256 CUs = 1024 >= 800

// --- static device scratch (d_ws proved too small; never touch it) ----------
__device__ float g_stats[256];            // sum1[64] sumsq1[64] sum2[32] sumsq2[32]
__device__ bf16  g_E1_0b[100000 * 64];    // 12.8 MB: emb0 @ W1_0^T in bf16
__device__ float g_E1_1[1000 * 64];
__device__ float g_E1_2[100 * 64];
__device__ float g_E1_3[50 * 64];
__device__ float g_U[8 * 64];
__device__ float g_Vb[64];
__device__ bf16  g_h1p[ROWS * 64];        // 26.2 MB bf16 h1_pre
__device__ bf16  g_h2p[ROWS * 32];        // 13.1 MB bf16 h2_pre
__device__ bf16  g_fmp[ROWS * 32];        // 13.1 MB bf16 FM partial

// software grid-barrier state (self-resetting; survives graph replays)
__device__ unsigned int g_bar_cnt = 0;
__device__ unsigned int g_bar_gen = 0;

__device__ __forceinline__ int clampi(int v, int hi) {
    return v < 0 ? 0 : (v > hi ? hi : v);
}
__device__ __forceinline__ float rl_f(float v, int l) {
    return __uint_as_float((unsigned int)__builtin_amdgcn_readlane((int)__float_as_uint(v), l));
}
__device__ __forceinline__ float us2f(unsigned short u) {
    return __uint_as_float(((unsigned int)u) << 16);
}

// 16B-granule XOR swizzles (involutions), used by stages C/D staging.
__device__ __forceinline__ int swz8(int d) {
    return (d & ~7) | ((d & 7) ^ ((d >> 3) & 7));
}
__device__ __forceinline__ int swz4(int d) {
    return (d & ~3) | ((d & 3) ^ (((d >> 2) ^ (d >> 4)) & 3));
}

// async global->LDS; LDS dest = uniform base + lane*size, global src per-lane.
#define GLOAD16(gp, lp)                                                        \
    __builtin_amdgcn_global_load_lds(                                          \
        (const __attribute__((address_space(1))) unsigned int*)(gp),           \
        (__attribute__((address_space(3))) unsigned int*)(lp), 16, 0, 0)

// ---------------------------------------------------------------------------
// Manual grid barrier (graph-capturable, unlike hipLaunchCooperativeKernel).
// Agent-scope ACQ_REL arrival = release of this block's prior stores (L2 wb);
// agent-scope ACQUIRE spin = invalidate before reading others' data.
// cnt resets to 0 BEFORE gen bump (release-ordered), so the pair is reusable
// across the 3 sync points and across graph replays.
// ---------------------------------------------------------------------------
__device__ __forceinline__ void grid_sync_sw() {
    __syncthreads();
    if (threadIdx.x == 0) {
        unsigned int g = __hip_atomic_load(&g_bar_gen, __ATOMIC_RELAXED,
                                           __HIP_MEMORY_SCOPE_AGENT);
        unsigned int t = __hip_atomic_fetch_add(&g_bar_cnt, 1u, __ATOMIC_ACQ_REL,
                                                __HIP_MEMORY_SCOPE_AGENT);
        if (t == NB - 1) {
            __hip_atomic_store(&g_bar_cnt, 0u, __ATOMIC_RELAXED,
                               __HIP_MEMORY_SCOPE_AGENT);
            __hip_atomic_fetch_add(&g_bar_gen, 1u, __ATOMIC_ACQ_REL,
                                   __HIP_MEMORY_SCOPE_AGENT);
        } else {
            while (__hip_atomic_load(&g_bar_gen, __ATOMIC_ACQUIRE,
                                     __HIP_MEMORY_SCOPE_AGENT) == g) {
                __builtin_amdgcn_s_sleep(2);
            }
        }
    }
    __syncthreads();
}

// ---------------------------------------------------------------------------
// ONE kernel, NB blocks x 256 threads, 3 software grid barriers.
// Co-residency: LDS 33.3KB -> 4 blocks/CU; VGPR<=128 (launch_bounds 256,4)
// -> 16 waves/CU; capacity 4*256=1024 >= 800.
//   stage A : table precompute (wave-slots 0..1150) + e10 (all 3200 slots)
//   stage B : phase1 (each wave-slot: 4 reps x 16 rows = 204800 rows)
//   stage C : phase2 (tile = slot)
//   stage D : phase3 (tile = slot)
// ---------------------------------------------------------------------------
__global__ __launch_bounds__(256, 4) void fused_kernel(
    const float* __restrict__ x,
    const float* __restrict__ emb0, const float* __restrict__ lin0,
    const float* __restrict__ emb1, const float* __restrict__ lin1,
    const float* __restrict__ emb2, const float* __restrict__ lin2,
    const float* __restrict__ emb3, const float* __restrict__ lin3,
    const float* __restrict__ cont_w, const float* __restrict__ cont_b,
    const float* __restrict__ clin_w, const float* __restrict__ clin_b,
    const float* __restrict__ fin_bias,
    const float* __restrict__ w1, const float* __restrict__ b1,
    const float* __restrict__ g1, const float* __restrict__ beta1,
    const float* __restrict__ w2, const float* __restrict__ b2,
    const float* __restrict__ g2, const float* __restrict__ beta2,
    const float* __restrict__ w_out, const float* __restrict__ b_out,
    float* __restrict__ out)
{
    __shared__ uint4 big[4][512];            // 32 KB, reused by stages C/D
    __shared__ float sa[64], sc[64], ls[64], lsum[64], lsq[64];

    int tid  = threadIdx.x;
    int lane = tid & 63;
    int wv   = tid >> 6;
    int d    = lane & 31;
    bool lo  = lane < 32;
    int slot = blockIdx.x * 4 + wv;          // 0..3199

    if (tid < 64) { lsum[tid] = 0.f; lsq[tid] = 0.f; }

    // ================= stage A: precompute + e10 ============================
    if (slot < 1150) {
        const float* tab; float* outp; int i, colOff;
        if (slot < 1000)      { tab = emb1; outp = g_E1_1; i = slot;        colOff = 32; }
        else if (slot < 1100) { tab = emb2; outp = g_E1_2; i = slot - 1000; colOff = 64; }
        else                  { tab = emb3; outp = g_E1_3; i = slot - 1100; colOff = 96; }
        float rv = tab[i * 32 + d];          // lanes 0..31 hold row[0..31]
        const float* wr = w1 + lane * 384 + colOff;
        float acc = 0.f;
        #pragma unroll
        for (int dd = 0; dd < 32; ++dd) acc = fmaf(rl_f(rv, dd), wr[dd], acc);
        outp[i * 64 + lane] = acc;
    } else if (slot == 1150) {
        int k = lane;
        g_stats[k]       = 0.f;
        g_stats[k + 64]  = 0.f;
        g_stats[k + 128] = 0.f;
        g_stats[k + 192] = 0.f;

        float vb = b1[k];
        #pragma unroll
        for (int j = 0; j < 8; ++j) {
            const float* wr = w1 + k * 384 + (4 + j) * 32;
            float u = 0.f;
            #pragma unroll
            for (int dd = 0; dd < 32; ++dd) {
                float w = wr[dd];
                u  = fmaf(cont_w[j * 32 + dd], w, u);
                vb = fmaf(cont_b[j * 32 + dd], w, vb);
            }
            g_U[j * 64 + k] = u;
        }
        g_Vb[k] = vb;
    }

    {   // e10 share: all 3200 wave-slots, 2 consecutive rows per iteration
        int h = lane >> 5;
        float w1col[32];
        const float4* wrv = (const float4*)(w1 + lane * 384);
        #pragma unroll
        for (int q = 0; q < 8; ++q) {
            float4 v = wrv[q];
            w1col[4*q+0] = v.x; w1col[4*q+1] = v.y;
            w1col[4*q+2] = v.z; w1col[4*q+3] = v.w;
        }
        for (int i = slot * 2; i < 100000; i += 6400) {
            int iA = i, iB = i + 1;
            float e = emb0[(h ? iB : iA) * 32 + d];
            float a0 = 0.f, a1 = 0.f, a2 = 0.f, a3 = 0.f;
            float b0 = 0.f, b1v = 0.f, b2v = 0.f, b3 = 0.f;
            #pragma unroll
            for (int dd = 0; dd < 32; dd += 4) {
                a0  = fmaf(rl_f(e, dd + 0),      w1col[dd + 0], a0);
                a1  = fmaf(rl_f(e, dd + 1),      w1col[dd + 1], a1);
                a2  = fmaf(rl_f(e, dd + 2),      w1col[dd + 2], a2);
                a3  = fmaf(rl_f(e, dd + 3),      w1col[dd + 3], a3);
                b0  = fmaf(rl_f(e, 32 + dd + 0), w1col[dd + 0], b0);
                b1v = fmaf(rl_f(e, 32 + dd + 1), w1col[dd + 1], b1v);
                b2v = fmaf(rl_f(e, 32 + dd + 2), w1col[dd + 2], b2v);
                b3  = fmaf(rl_f(e, 32 + dd + 3), w1col[dd + 3], b3);
            }
            g_E1_0b[iA * 64 + lane] = __float2bfloat16((a0 + a1) + (a2 + a3));
            g_E1_0b[iB * 64 + lane] = __float2bfloat16((b0 + b1v) + (b2v + b3));
        }
    }

    grid_sync_sw();   // tables ready

    // ================= stage B: phase1 (4 reps x 16 rows/wave) ==============
    {
        float uk[8];
        #pragma unroll
        for (int j = 0; j < 8; ++j) uk[j] = g_U[j * 64 + lane];
        float vbk = g_Vb[lane];

        float p1[8], p2[8], fb = 0.f;
        if (lo) {
            #pragma unroll
            for (int j = 0; j < 8; ++j) { p1[j] = cont_w[j * 32 + d]; p2[j] = cont_b[j * 32 + d]; }
        } else {
            #pragma unroll
            for (int j = 0; j < 8; ++j) { p1[j] = clin_w[j * 32 + d]; p2[j] = clin_b[j * 32 + d]; }
            fb = fin_bias[d];
        }

        const float* T0 = lo ? emb0 : lin0;
        const float* T1 = lo ? emb1 : lin1;
        const float* T2 = lo ? emb2 : lin2;
        const float* T3 = lo ? emb3 : lin3;

        float ss = 0.f, qq = 0.f;

        for (int rep = 0; rep < 4; ++rep) {
            int gw   = rep * 3200 + slot;    // 0..12799
            int base = gw * 16;

            float xs[4];
            #pragma unroll
            for (int g = 0; g < 4; ++g)
                xs[g] = (lane < 48) ? x[(base + 4 * g) * 12 + lane] : 0.f;

            float ga[2][4], gb[2][4], gc[2][4], gd[2][4], t1[2][4], t2[2][4], t3[2][4];
            unsigned short e0u[2][4];

            auto issue = [&](int g, int s) {
                #pragma unroll
                for (int t = 0; t < 4; ++t) {
                    int f  = t * 12;
                    int i0 = clampi((int)rl_f(xs[g], f + 0), 99999);
                    int i1 = clampi((int)rl_f(xs[g], f + 1), 999);
                    int i2 = clampi((int)rl_f(xs[g], f + 2), 99);
                    int i3 = clampi((int)rl_f(xs[g], f + 3), 49);
                    ga[s][t]  = T0[i0 * 32 + d];
                    gb[s][t]  = T1[i1 * 32 + d];
                    gc[s][t]  = T2[i2 * 32 + d];
                    gd[s][t]  = T3[i3 * 32 + d];
                    e0u[s][t] = ((const unsigned short*)g_E1_0b)[i0 * 64 + lane];
                    t1[s][t]  = g_E1_1[i1 * 64 + lane];
                    t2[s][t]  = g_E1_2[i2 * 64 + lane];
                    t3[s][t]  = g_E1_3[i3 * 64 + lane];
                }
            };

            issue(0, 0);

            #pragma unroll
            for (int g = 0; g < 4; ++g) {
                int s = g & 1;
                if (g < 3) issue(g + 1, (g + 1) & 1);

                #pragma unroll
                for (int t = 0; t < 4; ++t) {
                    int r  = base + 4 * g + t;
                    int fo = t * 12 + 4;
                    float xc[8];
                    #pragma unroll
                    for (int j = 0; j < 8; ++j) xc[j] = rl_f(xs[g], fo + j);

                    float va = ga[s][t], vb = gb[s][t], vc = gc[s][t], vd = gd[s][t];

                    float half_val;
                    if (lo) {
                        float s0 = va + vb, s1 = vc + vd;
                        float q0 = fmaf(va, va, vb * vb);
                        float q1 = fmaf(vc, vc, vd * vd);
                        #pragma unroll
                        for (int j = 0; j < 8; ++j) {
                            float ce = fmaf(xc[j], p1[j], p2[j]);
                            if (j & 1) { s1 += ce; q1 = fmaf(ce, ce, q1); }
                            else       { s0 += ce; q0 = fmaf(ce, ce, q0); }
                        }
                        float sfull = s0 + s1;
                        half_val = 0.5f * (sfull * sfull - (q0 + q1));   // interaction
                    } else {
                        float l0 = va + vb + fb, l1 = vc + vd;
                        #pragma unroll
                        for (int j = 0; j < 8; ++j) {
                            if (j & 1) l1 = fmaf(xc[j], p1[j], l1 + p2[j]);
                            else       l0 = fmaf(xc[j], p1[j], l0 + p2[j]);
                        }
                        half_val = l0 + l1;                              // linear
                    }
                    float other = __shfl(half_val, lane | 32);
                    if (lo) g_fmp[r * 32 + d] = __float2bfloat16(half_val + other);

                    float h1 = ((vbk + us2f(e0u[s][t])) + (t1[s][t] + t2[s][t])) + t3[s][t];
                    #pragma unroll
                    for (int j = 0; j < 8; ++j) h1 = fmaf(xc[j], uk[j], h1);

                    g_h1p[r * 64 + lane] = __float2bfloat16(h1);
                    ss += h1;
                    qq = fmaf(h1, h1, qq);
                }
            }
        }

        atomicAdd(&lsum[lane], ss);
        atomicAdd(&lsq[lane], qq);
        __syncthreads();
        if (tid < 64) {
            atomicAdd(&g_stats[tid], lsum[tid]);        // sum1
            atomicAdd(&g_stats[64 + tid], lsq[tid]);    // sumsq1
        }
    }

    grid_sync_sw();   // BN1 stats complete

    // ================= stage C: phase2 ======================================
    {
        size_t rowBase = (size_t)slot * 64;

        {
            const char* gsrc = (const char*)g_h1p + rowBase * 128;
            #pragma unroll
            for (int i = 0; i < 8; ++i) {
                int dlin = (i << 6) + lane;
                GLOAD16(gsrc + swz8(dlin) * 16, &big[wv][i << 6]);
            }
        }

        if (tid < 64) {
            float mu  = g_stats[tid] * N_INV;
            float var = g_stats[64 + tid] * N_INV - mu * mu;
            float a   = g1[tid] * rsqrtf(var + 1e-5f);
            sa[tid] = a;
            sc[tid] = beta1[tid] - a * mu;
            ls[tid] = 0.f;
        }
        __syncthreads();
        asm volatile("s_waitcnt vmcnt(0)" ::: "memory");

        const uint4* lrow = big[wv] + (lane << 3);
        int r7 = lane & 7;

        float acc[32];
        #pragma unroll
        for (int m = 0; m < 32; ++m) acc[m] = 0.f;

        #pragma unroll
        for (int half = 0; half < 2; ++half) {
            uint4 u[4];
            #pragma unroll
            for (int q = 0; q < 4; ++q) u[q] = lrow[(half * 4 + q) ^ r7];

            float y[32];
            #pragma unroll
            for (int q = 0; q < 4; ++q) {
                unsigned int w4[4] = {u[q].x, u[q].y, u[q].z, u[q].w};
                #pragma unroll
                for (int j = 0; j < 4; ++j) {
                    int i  = q * 4 + j;
                    int ch = half * 32 + 2 * i;
                    float f0 = __uint_as_float(w4[j] << 16);
                    float f1 = __uint_as_float(w4[j] & 0xffff0000u);
                    y[2*i]     = fmaxf(0.f, fmaf(sa[ch],     f0, sc[ch]));
                    y[2*i + 1] = fmaxf(0.f, fmaf(sa[ch + 1], f1, sc[ch + 1]));
                }
            }

            #pragma unroll
            for (int m = 0; m < 32; ++m) {
                const float* wr = w2 + m * 64 + half * 32;   // uniform -> scalar
                float a0 = 0.f, a1 = 0.f, a2 = 0.f, a3 = 0.f;
                #pragma unroll
                for (int k = 0; k < 32; k += 4) {
                    a0 = fmaf(y[k + 0], wr[k + 0], a0);
                    a1 = fmaf(y[k + 1], wr[k + 1], a1);
                    a2 = fmaf(y[k + 2], wr[k + 2], a2);
                    a3 = fmaf(y[k + 3], wr[k + 3], a3);
                }
                acc[m] += (a0 + a1) + (a2 + a3);
            }
        }

        #pragma unroll
        for (int m = 0; m < 32; ++m) acc[m] += b2[m];

        uint4 o[4];
        unsigned int* ow = (unsigned int*)o;
        #pragma unroll
        for (int i = 0; i < 16; ++i) {
            unsigned int lo16 = (unsigned int)__bfloat16_as_ushort(__float2bfloat16(acc[2*i]));
            unsigned int hi16 = (unsigned int)__bfloat16_as_ushort(__float2bfloat16(acc[2*i + 1]));
            ow[i] = lo16 | (hi16 << 16);
        }

        #pragma unroll
        for (int q = 0; q < 4; ++q) big[wv][swz4((lane << 2) + q)] = o[q];
        asm volatile("s_waitcnt lgkmcnt(0)" ::: "memory");
        {
            uint4* og = (uint4*)(g_h2p + rowBase * 32);
            #pragma unroll
            for (int i = 0; i < 4; ++i) {
                int dlin = (i << 6) + lane;
                og[dlin] = big[wv][swz4(dlin)];
            }
        }

        #pragma unroll
        for (int c0 = 0; c0 < 32; c0 += 8) {
            float s[8], q[8];
            #pragma unroll
            for (int j = 0; j < 8; ++j) { s[j] = acc[c0 + j]; q[j] = s[j] * s[j]; }
            #pragma unroll
            for (int off = 32; off >= 1; off >>= 1) {
                #pragma unroll
                for (int j = 0; j < 8; ++j) {
                    s[j] += __shfl_xor(s[j], off);
                    q[j] += __shfl_xor(q[j], off);
                }
            }
            if (lane == 0) {
                #pragma unroll
                for (int j = 0; j < 8; ++j) {
                    atomicAdd(&ls[c0 + j],      s[j]);
                    atomicAdd(&ls[32 + c0 + j], q[j]);
                }
            }
        }
        __syncthreads();
        if (tid < 32)       atomicAdd(&g_stats[128 + tid], ls[tid]);
        else if (tid < 64)  atomicAdd(&g_stats[160 + (tid - 32)], ls[tid]);
    }

    grid_sync_sw();   // BN2 stats complete

    // ================= stage D: phase3 ======================================
    {
        size_t rowBase = (size_t)slot * 64;

        {
            const char* gh2 = (const char*)g_h2p + rowBase * 64;
            const char* gfm = (const char*)g_fmp + rowBase * 64;
            #pragma unroll
            for (int i = 0; i < 4; ++i) {
                int dlin = (i << 6) + lane;
                GLOAD16(gh2 + swz4(dlin) * 16, &big[wv][i << 6]);
            }
            #pragma unroll
            for (int i = 0; i < 4; ++i) {
                int dlin = (i << 6) + lane;
                GLOAD16(gfm + swz4(dlin) * 16, &big[wv][256 + (i << 6)]);
            }
        }

        if (tid < 32) {
            float mu  = g_stats[128 + tid] * N_INV;
            float var = g_stats[160 + tid] * N_INV - mu * mu;
            float a   = g2[tid] * rsqrtf(var + 1e-5f);
            sa[tid] = a;
            sc[tid] = beta2[tid] - a * mu;
        }
        __syncthreads();
        asm volatile("s_waitcnt vmcnt(0)" ::: "memory");

        uint4 u[4], fm4[4];
        #pragma unroll
        for (int q = 0; q < 4; ++q) {
            int gidx = swz4((lane << 2) + q);
            u[q]   = big[wv][gidx];
            fm4[q] = big[wv][256 + gidx];
        }

        float y2[32];
        #pragma unroll
        for (int q = 0; q < 4; ++q) {
            unsigned int w4[4] = {u[q].x, u[q].y, u[q].z, u[q].w};
            #pragma unroll
            for (int j = 0; j < 4; ++j) {
                int i = q * 4 + j;
                float f0 = __uint_as_float(w4[j] << 16);
                float f1 = __uint_as_float(w4[j] & 0xffff0000u);
                y2[2*i]     = fmaxf(0.f, fmaf(sa[2*i],     f0, sc[2*i]));
                y2[2*i + 1] = fmaxf(0.f, fmaf(sa[2*i + 1], f1, sc[2*i + 1]));
            }
        }

        float fmv[32];
        {
            const unsigned int* fw = (const unsigned int*)fm4;
            #pragma unroll
            for (int i = 0; i < 16; ++i) {
                fmv[2*i]     = __uint_as_float(fw[i] << 16);
                fmv[2*i + 1] = __uint_as_float(fw[i] & 0xffff0000u);
            }
        }

        float res[32];
        #pragma unroll
        for (int dd = 0; dd < 32; ++dd) {
            const float* wr = w_out + dd * 32;           // uniform -> scalar
            float a0 = fmv[dd] + b_out[dd], a1 = 0.f, a2 = 0.f, a3 = 0.f;
            #pragma unroll
            for (int k = 0; k < 32; k += 4) {
                a0 = fmaf(y2[k + 0], wr[k + 0], a0);
                a1 = fmaf(y2[k + 1], wr[k + 1], a1);
                a2 = fmaf(y2[k + 2], wr[k + 2], a2);
                a3 = fmaf(y2[k + 3], wr[k + 3], a3);
            }
            res[dd] = (a0 + a1) + (a2 + a3);
        }

        #pragma unroll
        for (int q = 0; q < 8; ++q) {
            uint4 v;
            v.x = __float_as_uint(res[4*q+0]);
            v.y = __float_as_uint(res[4*q+1]);
            v.z = __float_as_uint(res[4*q+2]);
            v.w = __float_as_uint(res[4*q+3]);
            big[wv][swz8((lane << 3) + q)] = v;
        }
        asm volatile("s_waitcnt lgkmcnt(0)" ::: "memory");
        {
            uint4* og = (uint4*)(out + rowBase * 32);
            #pragma unroll
            for (int i = 0; i < 8; ++i) {
                int dlin = (i << 6) + lane;
                og[dlin] = big[wv][swz8(dlin)];
            }
        }
    }
}

// ---------------------------------------------------------------------------
extern "C" void kernel_launch(void* const* d_in, const int* in_sizes, int n_in,
                              void* d_out, int out_size, void* d_ws, size_t ws_size,
                              hipStream_t stream) {
    (void)in_sizes; (void)n_in; (void)out_size; (void)d_ws; (void)ws_size;

    // setup_inputs() dict order (emb/lin interleaved!) — all float32
    const float* x       = (const float*)d_in[0];
    const float* emb0    = (const float*)d_in[1];
    const float* lin0    = (const float*)d_in[2];
    const float* emb1    = (const float*)d_in[3];
    const float* lin1    = (const float*)d_in[4];
    const float* emb2    = (const float*)d_in[5];
    const float* lin2    = (const float*)d_in[6];
    const float* emb3    = (const float*)d_in[7];
    const float* lin3    = (const float*)d_in[8];
    const float* cont_w  = (const float*)d_in[9];
    const float* cont_b  = (const float*)d_in[10];
    const float* clin_w  = (const float*)d_in[11];
    const float* clin_b  = (const float*)d_in[12];
    const float* fin_bias= (const float*)d_in[13];
    const float* w1      = (const float*)d_in[14];
    const float* b1      = (const float*)d_in[15];
    const float* g1      = (const float*)d_in[16];
    const float* beta1   = (const float*)d_in[17];
    const float* w2      = (const float*)d_in[18];
    const float* b2      = (const float*)d_in[19];
    const float* g2      = (const float*)d_in[20];
    const float* beta2   = (const float*)d_in[21];
    const float* w_out   = (const float*)d_in[22];
    const float* b_out   = (const float*)d_in[23];

    float* outp = (float*)d_out;

    hipLaunchKernelGGL(fused_kernel, dim3(NB), dim3(256), 0, stream,
                       x, emb0, lin0, emb1, lin1, emb2, lin2, emb3, lin3,
                       cont_w, cont_b, clin_w, clin_b, fin_bias,
                       w1, b1, g1, beta1, w2, b2, g2, beta2,
                       w_out, b_out, outp);
}

// Round 6
// 352.618 us; speedup vs baseline: 2.1333x; 2.1333x over previous
//
#include <hip/hip_runtime.h>
#include <hip/hip_bf16.h>

typedef __hip_bfloat16 bf16;

#define ROWS 204800
#define N_INV (1.0f / 204800.0f)

// --- static device scratch (d_ws proved too small; never touch it) ----------
__device__ float g_stats[256];            // sum1[64] sumsq1[64] sum2[32] sumsq2[32]
__device__ bf16  g_E1_0b[100000 * 64];    // 12.8 MB: emb0 @ W1_0^T in bf16
__device__ float g_E1_1[1000 * 64];
__device__ float g_E1_2[100 * 64];
__device__ float g_E1_3[50 * 64];
__device__ float g_U[8 * 64];
__device__ float g_Vb[64];
__device__ bf16  g_h1p[ROWS * 64];        // 26.2 MB bf16 h1_pre
__device__ bf16  g_h2p[ROWS * 32];        // 13.1 MB bf16 h2_pre
__device__ bf16  g_fmp[ROWS * 32];        // 13.1 MB bf16 FM partial

__device__ __forceinline__ int clampi(int v, int hi) {
    return v < 0 ? 0 : (v > hi ? hi : v);
}
__device__ __forceinline__ float rl_f(float v, int l) {
    return __uint_as_float((unsigned int)__builtin_amdgcn_readlane((int)__float_as_uint(v), l));
}
__device__ __forceinline__ float us2f(unsigned short u) {
    return __uint_as_float(((unsigned int)u) << 16);
}

// 16B-granule XOR swizzles (involutions), used by phase2/3 staging.
__device__ __forceinline__ int swz8(int d) {
    return (d & ~7) | ((d & 7) ^ ((d >> 3) & 7));
}
__device__ __forceinline__ int swz4(int d) {
    return (d & ~3) | ((d & 3) ^ (((d >> 2) ^ (d >> 4)) & 3));
}

// async global->LDS; LDS dest = uniform base + lane*size, global src per-lane.
#define GLOAD16(gp, lp)                                                        \
    __builtin_amdgcn_global_load_lds(                                          \
        (const __attribute__((address_space(1))) unsigned int*)(gp),           \
        (__attribute__((address_space(3))) unsigned int*)(lp), 16, 0, 0)
#define GLOAD4(gp, lp)                                                         \
    __builtin_amdgcn_global_load_lds(                                          \
        (const __attribute__((address_space(1))) unsigned int*)(gp),           \
        (__attribute__((address_space(3))) unsigned int*)(lp), 4, 0, 0)

// Counted drain. In-order vmcnt retirement: vmcnt(K) guarantees an op X has
// retired whenever >=K VMEM ops were issued after X. At every use below, our
// own newer-op count is >=63, so VWAIT(63) is a correct drain for the target
// slot while leaving up to 63 ops in flight (deep pipeline preserved).
#define VWAIT(n)                                                               \
    do {                                                                       \
        asm volatile("s_waitcnt vmcnt(" #n ")" ::: "memory");                  \
        __builtin_amdgcn_sched_barrier(0);                                     \
    } while (0)

// ---------------------------------------------------------------------------
// Kernel A: E1_t = emb_t @ W1_t^T (t=1..3), U = cont_w @ W1_cont^T,
// Vb = b1 + sum_j cont_b[j] @ W1_cont_j^T. Block 1150 zeroes the stat block.
// ---------------------------------------------------------------------------
__global__ __launch_bounds__(64) void precompute_kernel(
    const float* __restrict__ emb1, const float* __restrict__ emb2, const float* __restrict__ emb3,
    const float* __restrict__ cont_w, const float* __restrict__ cont_b,
    const float* __restrict__ w1, const float* __restrict__ b1)
{
    int b = blockIdx.x;
    int k = threadIdx.x;
    __shared__ float row[32];

    if (b < 1150) {
        const float* tab; float* out; int i, colOff;
        if (b < 1000)      { tab = emb1; out = g_E1_1; i = b;        colOff = 32; }
        else if (b < 1100) { tab = emb2; out = g_E1_2; i = b - 1000; colOff = 64; }
        else               { tab = emb3; out = g_E1_3; i = b - 1100; colOff = 96; }
        if (k < 32) row[k] = tab[i * 32 + k];
        __syncthreads();
        const float* wr = w1 + k * 384 + colOff;
        float acc = 0.f;
        #pragma unroll
        for (int d = 0; d < 32; ++d) acc = fmaf(row[d], wr[d], acc);
        out[i * 64 + k] = acc;
    } else {
        g_stats[k]       = 0.f;
        g_stats[k + 64]  = 0.f;
        g_stats[k + 128] = 0.f;
        g_stats[k + 192] = 0.f;

        float vb = b1[k];
        #pragma unroll
        for (int j = 0; j < 8; ++j) {
            const float* wr = w1 + k * 384 + (4 + j) * 32;
            float u = 0.f;
            #pragma unroll
            for (int d = 0; d < 32; ++d) {
                float w = wr[d];
                u  = fmaf(cont_w[j * 32 + d], w, u);
                vb = fmaf(cont_b[j * 32 + d], w, vb);
            }
            g_U[j * 64 + k] = u;
        }
        g_Vb[k] = vb;
    }
}

// ---------------------------------------------------------------------------
// e10: E1_0 = emb0 @ W1_0^T (100000 x 64) bf16. TWO rows per wave-iteration.
// ---------------------------------------------------------------------------
__global__ __launch_bounds__(256) void e10_kernel(
    const float* __restrict__ emb0, const float* __restrict__ w1)
{
    int lane = threadIdx.x & 63;
    int wv   = threadIdx.x >> 6;
    int h    = lane >> 5;

    float w1col[32];
    {
        const float4* wr = (const float4*)(w1 + lane * 384);
        #pragma unroll
        for (int q = 0; q < 8; ++q) {
            float4 v = wr[q];
            w1col[4*q+0] = v.x; w1col[4*q+1] = v.y;
            w1col[4*q+2] = v.z; w1col[4*q+3] = v.w;
        }
    }

    for (int i = blockIdx.x * 8 + wv * 2; i < 100000; i += gridDim.x * 8) {
        int iA = i, iB = i + 1;
        float e = emb0[(h ? iB : iA) * 32 + (lane & 31)];

        float a0 = 0.f, a1 = 0.f, a2 = 0.f, a3 = 0.f;
        float b0 = 0.f, b1v = 0.f, b2v = 0.f, b3 = 0.f;
        #pragma unroll
        for (int dd = 0; dd < 32; dd += 4) {
            a0  = fmaf(rl_f(e, dd + 0),      w1col[dd + 0], a0);
            a1  = fmaf(rl_f(e, dd + 1),      w1col[dd + 1], a1);
            a2  = fmaf(rl_f(e, dd + 2),      w1col[dd + 2], a2);
            a3  = fmaf(rl_f(e, dd + 3),      w1col[dd + 3], a3);
            b0  = fmaf(rl_f(e, 32 + dd + 0), w1col[dd + 0], b0);
            b1v = fmaf(rl_f(e, 32 + dd + 1), w1col[dd + 1], b1v);
            b2v = fmaf(rl_f(e, 32 + dd + 2), w1col[dd + 2], b2v);
            b3  = fmaf(rl_f(e, 32 + dd + 3), w1col[dd + 3], b3);
        }
        g_E1_0b[iA * 64 + lane] = __float2bfloat16((a0 + a1) + (a2 + a3));
        g_E1_0b[iB * 64 + lane] = __float2bfloat16((b0 + b1v) + (b2v + b3));
    }
}

// ---------------------------------------------------------------------------
// Phase 1: 16 rows/wave in 4 groups. ALL long-latency gathers (emb0/lin0 row
// "va" + E1_0b row "e0u") for all 4 groups are issued up-front into 4 distinct
// LDS slots (32 loads in flight/wave); each group drained with VWAIT(63)
// (correct by the in-order-retirement counting rule — see macro comment).
// Short gathers (L2-resident tables) stay register-loaded, 2-slot.
// ---------------------------------------------------------------------------
__global__ __launch_bounds__(256, 4) void phase1_kernel(
    const float* __restrict__ x,
    const float* __restrict__ emb0, const float* __restrict__ lin0,
    const float* __restrict__ emb1, const float* __restrict__ lin1,
    const float* __restrict__ emb2, const float* __restrict__ lin2,
    const float* __restrict__ emb3, const float* __restrict__ lin3,
    const float* __restrict__ cont_w, const float* __restrict__ cont_b,
    const float* __restrict__ clin_w, const float* __restrict__ clin_b,
    const float* __restrict__ fin_bias)
{
    __shared__ float lsum[64], lsq[64];
    __shared__ float          s_va[4][4][256];   // [wave][slot][row*64+lane]
    __shared__ unsigned short s_e0[4][4][256];   // [wave][slot][row*64+lane]

    int tid  = threadIdx.x;
    int lane = tid & 63;
    int wv   = tid >> 6;
    int d    = lane & 31;
    bool lo  = lane < 32;

    if (tid < 64) { lsum[tid] = 0.f; lsq[tid] = 0.f; }
    __syncthreads();

    float uk[8];
    #pragma unroll
    for (int j = 0; j < 8; ++j) uk[j] = g_U[j * 64 + lane];
    float vbk = g_Vb[lane];

    float p1[8], p2[8], fb = 0.f;
    if (lo) {
        #pragma unroll
        for (int j = 0; j < 8; ++j) { p1[j] = cont_w[j * 32 + d]; p2[j] = cont_b[j * 32 + d]; }
    } else {
        #pragma unroll
        for (int j = 0; j < 8; ++j) { p1[j] = clin_w[j * 32 + d]; p2[j] = clin_b[j * 32 + d]; }
        fb = fin_bias[d];
    }

    const float* T0 = lo ? emb0 : lin0;
    const float* T1 = lo ? emb1 : lin1;
    const float* T2 = lo ? emb2 : lin2;
    const float* T3 = lo ? emb3 : lin3;

    int gw   = blockIdx.x * 4 + wv;        // 0..12799
    int base = gw * 16;

    float xs[4];
    #pragma unroll
    for (int g = 0; g < 4; ++g)
        xs[g] = (lane < 48) ? x[(base + 4 * g) * 12 + lane] : 0.f;

    float gb[2][4], gc[2][4], gd[2][4], t1[2][4], t2[2][4], t3[2][4];

    // ---- long-latency staging: va (emb0/lin0 row) + e0 (E1_0b row) --------
    auto issueL = [&](int g, int slot) {
        #pragma unroll
        for (int t = 0; t < 4; ++t) {
            int i0 = clampi((int)rl_f(xs[g], t * 12), 99999);
            GLOAD4(T0 + i0 * 32 + d, &s_va[wv][slot][t * 64]);
            if (lane < 32) {
                const unsigned int* pe0 =
                    (const unsigned int*)((const unsigned short*)g_E1_0b + i0 * 64) + lane;
                GLOAD4(pe0, &s_e0[wv][slot][t * 64]);
            }
        }
    };

    // ---- short-latency gathers (L1/L2-resident tables), 2-slot as before --
    auto issueC = [&](int g, int s) {
        #pragma unroll
        for (int t = 0; t < 4; ++t) {
            int f  = t * 12;
            int i1 = clampi((int)rl_f(xs[g], f + 1), 999);
            int i2 = clampi((int)rl_f(xs[g], f + 2), 99);
            int i3 = clampi((int)rl_f(xs[g], f + 3), 49);
            gb[s][t] = T1[i1 * 32 + d];
            gc[s][t] = T2[i2 * 32 + d];
            gd[s][t] = T3[i3 * 32 + d];
            t1[s][t] = g_E1_1[i1 * 64 + lane];
            t2[s][t] = g_E1_2[i2 * 64 + lane];
            t3[s][t] = g_E1_3[i3 * 64 + lane];
        }
    };

    float ss = 0.f, qq = 0.f;

    auto compute = [&](int g, int slot, int cs) {
        #pragma unroll
        for (int t = 0; t < 4; ++t) {
            int r  = base + 4 * g + t;
            int fo = t * 12 + 4;
            float xc[8];
            #pragma unroll
            for (int j = 0; j < 8; ++j) xc[j] = rl_f(xs[g], fo + j);

            float va  = s_va[wv][slot][t * 64 + lane];
            float e0f = us2f(s_e0[wv][slot][t * 64 + lane]);
            float vb = gb[cs][t], vc = gc[cs][t], vd = gd[cs][t];

            float half_val;
            if (lo) {
                float s0 = va + vb, s1 = vc + vd;
                float q0 = fmaf(va, va, vb * vb);
                float q1 = fmaf(vc, vc, vd * vd);
                #pragma unroll
                for (int j = 0; j < 8; ++j) {
                    float ce = fmaf(xc[j], p1[j], p2[j]);
                    if (j & 1) { s1 += ce; q1 = fmaf(ce, ce, q1); }
                    else       { s0 += ce; q0 = fmaf(ce, ce, q0); }
                }
                float sfull = s0 + s1;
                half_val = 0.5f * (sfull * sfull - (q0 + q1));   // interaction
            } else {
                float l0 = va + vb + fb, l1 = vc + vd;
                #pragma unroll
                for (int j = 0; j < 8; ++j) {
                    if (j & 1) l1 = fmaf(xc[j], p1[j], l1 + p2[j]);
                    else       l0 = fmaf(xc[j], p1[j], l0 + p2[j]);
                }
                half_val = l0 + l1;                              // linear
            }
            float other = __shfl(half_val, lane | 32);
            if (lo) g_fmp[r * 32 + d] = __float2bfloat16(half_val + other);

            float h1 = ((vbk + e0f) + (t1[cs][t] + t2[cs][t])) + t3[cs][t];
            #pragma unroll
            for (int j = 0; j < 8; ++j) h1 = fmaf(xc[j], uk[j], h1);

            g_h1p[r * 64 + lane] = __float2bfloat16(h1);
            ss += h1;
            qq = fmaf(h1, h1, qq);
        }
    };

    // Deep pipeline: all 32 long gathers in flight, VWAIT(63) per group.
    // Newer-op lower bounds at each drain (our ops only):
    //  c0: L1+L2+L3(24) + C0+C1(48) = 72 >= 63
    //  c1: L2+L3(16) + C0..C2(72) + st0(8) = 96 >= 63
    //  c2: L3(8) + C0..C3(96) + st(16) = 120 >= 63
    //  c3: C0..C3(96) + st(24) = 120 >= 63
    issueL(0, 0); issueL(1, 1); issueL(2, 2); issueL(3, 3);
    issueC(0, 0); issueC(1, 1);

    VWAIT(63); compute(0, 0, 0);
    issueC(2, 0);
    VWAIT(63); compute(1, 1, 1);
    issueC(3, 1);
    VWAIT(63); compute(2, 2, 0);
    VWAIT(63); compute(3, 3, 1);

    atomicAdd(&lsum[lane], ss);
    atomicAdd(&lsq[lane], qq);
    __syncthreads();
    if (tid < 64) {
        atomicAdd(&g_stats[tid], lsum[tid]);        // sum1
        atomicAdd(&g_stats[64 + tid], lsq[tid]);    // sumsq1
    }
}

// ---------------------------------------------------------------------------
// Phase 2 (row-per-lane, LDS-staged; unchanged).
// ---------------------------------------------------------------------------
__global__ __launch_bounds__(256) void phase2_kernel(
    const float* __restrict__ w2, const float* __restrict__ b2,
    const float* __restrict__ g1, const float* __restrict__ beta1)
{
    __shared__ float sa[64], sc[64];
    __shared__ float ls[64];                 // ls[m]=sum2, ls[32+m]=sumsq2
    __shared__ uint4 hbuf[4][512];           // 4 waves x 8 KB (wave-private)

    int tid  = threadIdx.x;
    int lane = tid & 63;
    int wv   = tid >> 6;
    size_t rowBase = (size_t)(blockIdx.x * 4 + wv) * 64;

    {
        const char* gsrc = (const char*)g_h1p + rowBase * 128;
        #pragma unroll
        for (int i = 0; i < 8; ++i) {
            int dlin = (i << 6) + lane;
            GLOAD16(gsrc + swz8(dlin) * 16, &hbuf[wv][i << 6]);
        }
    }

    if (tid < 64) {
        float mu  = g_stats[tid] * N_INV;
        float var = g_stats[64 + tid] * N_INV - mu * mu;
        float a   = g1[tid] * rsqrtf(var + 1e-5f);
        sa[tid] = a;
        sc[tid] = beta1[tid] - a * mu;
        ls[tid] = 0.f;
    }
    __syncthreads();
    asm volatile("s_waitcnt vmcnt(0)" ::: "memory");

    const uint4* lrow = hbuf[wv] + (lane << 3);
    int r7 = lane & 7;

    float acc[32];
    #pragma unroll
    for (int m = 0; m < 32; ++m) acc[m] = 0.f;

    #pragma unroll
    for (int half = 0; half < 2; ++half) {
        uint4 u[4];
        #pragma unroll
        for (int q = 0; q < 4; ++q) u[q] = lrow[(half * 4 + q) ^ r7];

        float y[32];
        #pragma unroll
        for (int q = 0; q < 4; ++q) {
            unsigned int w4[4] = {u[q].x, u[q].y, u[q].z, u[q].w};
            #pragma unroll
            for (int j = 0; j < 4; ++j) {
                int i  = q * 4 + j;
                int ch = half * 32 + 2 * i;
                float f0 = __uint_as_float(w4[j] << 16);
                float f1 = __uint_as_float(w4[j] & 0xffff0000u);
                y[2*i]     = fmaxf(0.f, fmaf(sa[ch],     f0, sc[ch]));
                y[2*i + 1] = fmaxf(0.f, fmaf(sa[ch + 1], f1, sc[ch + 1]));
            }
        }

        #pragma unroll
        for (int m = 0; m < 32; ++m) {
            const float* wr = w2 + m * 64 + half * 32;   // uniform -> scalar
            float a0 = 0.f, a1 = 0.f, a2 = 0.f, a3 = 0.f;
            #pragma unroll
            for (int k = 0; k < 32; k += 4) {
                a0 = fmaf(y[k + 0], wr[k + 0], a0);
                a1 = fmaf(y[k + 1], wr[k + 1], a1);
                a2 = fmaf(y[k + 2], wr[k + 2], a2);
                a3 = fmaf(y[k + 3], wr[k + 3], a3);
            }
            acc[m] += (a0 + a1) + (a2 + a3);
        }
    }

    #pragma unroll
    for (int m = 0; m < 32; ++m) acc[m] += b2[m];

    uint4 o[4];
    unsigned int* ow = (unsigned int*)o;
    #pragma unroll
    for (int i = 0; i < 16; ++i) {
        unsigned int lo16 = (unsigned int)__bfloat16_as_ushort(__float2bfloat16(acc[2*i]));
        unsigned int hi16 = (unsigned int)__bfloat16_as_ushort(__float2bfloat16(acc[2*i + 1]));
        ow[i] = lo16 | (hi16 << 16);
    }

    #pragma unroll
    for (int q = 0; q < 4; ++q) hbuf[wv][swz4((lane << 2) + q)] = o[q];
    asm volatile("s_waitcnt lgkmcnt(0)" ::: "memory");
    {
        uint4* og = (uint4*)(g_h2p + rowBase * 32);
        #pragma unroll
        for (int i = 0; i < 4; ++i) {
            int dlin = (i << 6) + lane;
            og[dlin] = hbuf[wv][swz4(dlin)];
        }
    }

    #pragma unroll
    for (int c0 = 0; c0 < 32; c0 += 8) {
        float s[8], q[8];
        #pragma unroll
        for (int j = 0; j < 8; ++j) { s[j] = acc[c0 + j]; q[j] = s[j] * s[j]; }
        #pragma unroll
        for (int off = 32; off >= 1; off >>= 1) {
            #pragma unroll
            for (int j = 0; j < 8; ++j) {
                s[j] += __shfl_xor(s[j], off);
                q[j] += __shfl_xor(q[j], off);
            }
        }
        if (lane == 0) {
            #pragma unroll
            for (int j = 0; j < 8; ++j) {
                atomicAdd(&ls[c0 + j],      s[j]);
                atomicAdd(&ls[32 + c0 + j], q[j]);
            }
        }
    }
    __syncthreads();
    if (tid < 32)       atomicAdd(&g_stats[128 + tid], ls[tid]);
    else if (tid < 64)  atomicAdd(&g_stats[160 + (tid - 32)], ls[tid]);
}

// ---------------------------------------------------------------------------
// Phase 3 (row-per-lane, LDS-staged; unchanged).
// ---------------------------------------------------------------------------
__global__ __launch_bounds__(256) void phase3_kernel(
    const float* __restrict__ w_out, const float* __restrict__ b_out,
    const float* __restrict__ g2, const float* __restrict__ beta2,
    float* __restrict__ out)
{
    __shared__ float sa[32], sc[32];
    __shared__ uint4 sbuf[4][512];           // per wave: [0,256)=h2, [256,512)=fm

    int tid  = threadIdx.x;
    int lane = tid & 63;
    int wv   = tid >> 6;
    size_t rowBase = (size_t)(blockIdx.x * 4 + wv) * 64;

    {
        const char* gh2 = (const char*)g_h2p + rowBase * 64;
        const char* gfm = (const char*)g_fmp + rowBase * 64;
        #pragma unroll
        for (int i = 0; i < 4; ++i) {
            int dlin = (i << 6) + lane;
            GLOAD16(gh2 + swz4(dlin) * 16, &sbuf[wv][i << 6]);
        }
        #pragma unroll
        for (int i = 0; i < 4; ++i) {
            int dlin = (i << 6) + lane;
            GLOAD16(gfm + swz4(dlin) * 16, &sbuf[wv][256 + (i << 6)]);
        }
    }

    if (tid < 32) {
        float mu  = g_stats[128 + tid] * N_INV;
        float var = g_stats[160 + tid] * N_INV - mu * mu;
        float a   = g2[tid] * rsqrtf(var + 1e-5f);
        sa[tid] = a;
        sc[tid] = beta2[tid] - a * mu;
    }
    __syncthreads();
    asm volatile("s_waitcnt vmcnt(0)" ::: "memory");

    uint4 u[4], fm4[4];
    #pragma unroll
    for (int q = 0; q < 4; ++q) {
        int gidx = swz4((lane << 2) + q);
        u[q]   = sbuf[wv][gidx];
        fm4[q] = sbuf[wv][256 + gidx];
    }

    float y2[32];
    #pragma unroll
    for (int q = 0; q < 4; ++q) {
        unsigned int w4[4] = {u[q].x, u[q].y, u[q].z, u[q].w};
        #pragma unroll
        for (int j = 0; j < 4; ++j) {
            int i = q * 4 + j;
            float f0 = __uint_as_float(w4[j] << 16);
            float f1 = __uint_as_float(w4[j] & 0xffff0000u);
            y2[2*i]     = fmaxf(0.f, fmaf(sa[2*i],     f0, sc[2*i]));
            y2[2*i + 1] = fmaxf(0.f, fmaf(sa[2*i + 1], f1, sc[2*i + 1]));
        }
    }

    float fmv[32];
    {
        const unsigned int* fw = (const unsigned int*)fm4;
        #pragma unroll
        for (int i = 0; i < 16; ++i) {
            fmv[2*i]     = __uint_as_float(fw[i] << 16);
            fmv[2*i + 1] = __uint_as_float(fw[i] & 0xffff0000u);
        }
    }

    float res[32];
    #pragma unroll
    for (int dd = 0; dd < 32; ++dd) {
        const float* wr = w_out + dd * 32;           // uniform -> scalar
        float a0 = fmv[dd] + b_out[dd], a1 = 0.f, a2 = 0.f, a3 = 0.f;
        #pragma unroll
        for (int k = 0; k < 32; k += 4) {
            a0 = fmaf(y2[k + 0], wr[k + 0], a0);
            a1 = fmaf(y2[k + 1], wr[k + 1], a1);
            a2 = fmaf(y2[k + 2], wr[k + 2], a2);
            a3 = fmaf(y2[k + 3], wr[k + 3], a3);
        }
        res[dd] = (a0 + a1) + (a2 + a3);
    }

    #pragma unroll
    for (int q = 0; q < 8; ++q) {
        uint4 v;
        v.x = __float_as_uint(res[4*q+0]);
        v.y = __float_as_uint(res[4*q+1]);
        v.z = __float_as_uint(res[4*q+2]);
        v.w = __float_as_uint(res[4*q+3]);
        sbuf[wv][swz8((lane << 3) + q)] = v;
    }
    asm volatile("s_waitcnt lgkmcnt(0)" ::: "memory");
    {
        uint4* og = (uint4*)(out + rowBase * 32);
        #pragma unroll
        for (int i = 0; i < 8; ++i) {
            int dlin = (i << 6) + lane;
            og[dlin] = sbuf[wv][swz8(dlin)];
        }
    }
}

// ---------------------------------------------------------------------------
extern "C" void kernel_launch(void* const* d_in, const int* in_sizes, int n_in,
                              void* d_out, int out_size, void* d_ws, size_t ws_size,
                              hipStream_t stream) {
    (void)in_sizes; (void)n_in; (void)out_size; (void)d_ws; (void)ws_size;

    // setup_inputs() dict order (emb/lin interleaved!) — all float32
    const float* x       = (const float*)d_in[0];
    const float* emb0    = (const float*)d_in[1];
    const float* lin0    = (const float*)d_in[2];
    const float* emb1    = (const float*)d_in[3];
    const float* lin1    = (const float*)d_in[4];
    const float* emb2    = (const float*)d_in[5];
    const float* lin2    = (const float*)d_in[6];
    const float* emb3    = (const float*)d_in[7];
    const float* lin3    = (const float*)d_in[8];
    const float* cont_w  = (const float*)d_in[9];
    const float* cont_b  = (const float*)d_in[10];
    const float* clin_w  = (const float*)d_in[11];
    const float* clin_b  = (const float*)d_in[12];
    const float* fin_bias= (const float*)d_in[13];
    const float* w1      = (const float*)d_in[14];
    const float* b1      = (const float*)d_in[15];
    const float* g1      = (const float*)d_in[16];
    const float* beta1   = (const float*)d_in[17];
    const float* w2      = (const float*)d_in[18];
    const float* b2      = (const float*)d_in[19];
    const float* g2      = (const float*)d_in[20];
    const float* beta2   = (const float*)d_in[21];
    const float* w_out   = (const float*)d_in[22];
    const float* b_out   = (const float*)d_in[23];

    float* outp = (float*)d_out;

    hipLaunchKernelGGL(precompute_kernel, dim3(1151), dim3(64), 0, stream,
                       emb1, emb2, emb3, cont_w, cont_b, w1, b1);

    hipLaunchKernelGGL(e10_kernel, dim3(1600), dim3(256), 0, stream, emb0, w1);

    hipLaunchKernelGGL(phase1_kernel, dim3(3200), dim3(256), 0, stream,
                       x, emb0, lin0, emb1, lin1, emb2, lin2, emb3, lin3,
                       cont_w, cont_b, clin_w, clin_b, fin_bias);

    hipLaunchKernelGGL(phase2_kernel, dim3(800), dim3(256), 0, stream,
                       w2, b2, g1, beta1);

    hipLaunchKernelGGL(phase3_kernel, dim3(800), dim3(256), 0, stream,
                       w_out, b_out, g2, beta2, outp);
}

// Round 7
// 335.233 us; speedup vs baseline: 2.2440x; 1.0519x over previous
//
#include <hip/hip_runtime.h>
#include <hip/hip_bf16.h>

typedef __hip_bfloat16 bf16;

#define ROWS 204800
#define N_INV (1.0f / 204800.0f)

// --- static device scratch (d_ws proved too small; never touch it) ----------
__device__ float g_stats[256];            // sum1[64] sumsq1[64] sum2[32] sumsq2[32]
__device__ float g_E1_1[1000 * 64];
__device__ float g_E1_2[100 * 64];
__device__ float g_E1_3[50 * 64];
__device__ float g_U[8 * 64];
__device__ float g_Vb[64];
__device__ bf16  g_h1p[ROWS * 64];        // 26.2 MB bf16 h1_pre
__device__ bf16  g_h2p[ROWS * 32];        // 13.1 MB bf16 h2_pre
__device__ bf16  g_fmp[ROWS * 32];        // 13.1 MB bf16 FM partial

__device__ __forceinline__ int clampi(int v, int hi) {
    return v < 0 ? 0 : (v > hi ? hi : v);
}
__device__ __forceinline__ float rl_f(float v, int l) {
    return __uint_as_float((unsigned int)__builtin_amdgcn_readlane((int)__float_as_uint(v), l));
}

// 16B-granule XOR swizzles (involutions), used by phase2/3 staging.
__device__ __forceinline__ int swz8(int d) {
    return (d & ~7) | ((d & 7) ^ ((d >> 3) & 7));
}
__device__ __forceinline__ int swz4(int d) {
    return (d & ~3) | ((d & 3) ^ (((d >> 2) ^ (d >> 4)) & 3));
}

// async global->LDS; LDS dest = uniform base + lane*size, global src per-lane.
#define GLOAD16(gp, lp)                                                        \
    __builtin_amdgcn_global_load_lds(                                          \
        (const __attribute__((address_space(1))) unsigned int*)(gp),           \
        (__attribute__((address_space(3))) unsigned int*)(lp), 16, 0, 0)

// ---------------------------------------------------------------------------
// Kernel A: E1_t = emb_t @ W1_t^T (t=1..3), U = cont_w @ W1_cont^T,
// Vb = b1 + sum_j cont_b[j] @ W1_cont_j^T. Block 1150 zeroes the stat block.
// ---------------------------------------------------------------------------
__global__ __launch_bounds__(64) void precompute_kernel(
    const float* __restrict__ emb1, const float* __restrict__ emb2, const float* __restrict__ emb3,
    const float* __restrict__ cont_w, const float* __restrict__ cont_b,
    const float* __restrict__ w1, const float* __restrict__ b1)
{
    int b = blockIdx.x;
    int k = threadIdx.x;
    __shared__ float row[32];

    if (b < 1150) {
        const float* tab; float* out; int i, colOff;
        if (b < 1000)      { tab = emb1; out = g_E1_1; i = b;        colOff = 32; }
        else if (b < 1100) { tab = emb2; out = g_E1_2; i = b - 1000; colOff = 64; }
        else               { tab = emb3; out = g_E1_3; i = b - 1100; colOff = 96; }
        if (k < 32) row[k] = tab[i * 32 + k];
        __syncthreads();
        const float* wr = w1 + k * 384 + colOff;
        float acc = 0.f;
        #pragma unroll
        for (int d = 0; d < 32; ++d) acc = fmaf(row[d], wr[d], acc);
        out[i * 64 + k] = acc;
    } else {
        g_stats[k]       = 0.f;
        g_stats[k + 64]  = 0.f;
        g_stats[k + 128] = 0.f;
        g_stats[k + 192] = 0.f;

        float vb = b1[k];
        #pragma unroll
        for (int j = 0; j < 8; ++j) {
            const float* wr = w1 + k * 384 + (4 + j) * 32;
            float u = 0.f;
            #pragma unroll
            for (int d = 0; d < 32; ++d) {
                float w = wr[d];
                u  = fmaf(cont_w[j * 32 + d], w, u);
                vb = fmaf(cont_b[j * 32 + d], w, vb);
            }
            g_U[j * 64 + k] = u;
        }
        g_Vb[k] = vb;
    }
}

// ---------------------------------------------------------------------------
// Phase 1 (traffic-reduced): the E1_0b stream is GONE. The emb0 row already
// sits in lanes 0-31 of va; E1_0[i0][lane] = sum_d rl_f(va,d)*W1[lane][d] is
// computed inline (32 readlane+FMA per row vs a 12.8 MB HBM stream + the
// entire e10 kernel). Four prior structural variants (sunk / 2-slot reg /
// LDS 2-ahead / LDS 4-ahead) all measured 118-123 us => structure-invariant,
// traffic-bound. Simple single-slot gather structure, fits 128-VGPR cap.
// ---------------------------------------------------------------------------
__global__ __launch_bounds__(256, 4) void phase1_kernel(
    const float* __restrict__ x,
    const float* __restrict__ emb0, const float* __restrict__ lin0,
    const float* __restrict__ emb1, const float* __restrict__ lin1,
    const float* __restrict__ emb2, const float* __restrict__ lin2,
    const float* __restrict__ emb3, const float* __restrict__ lin3,
    const float* __restrict__ cont_w, const float* __restrict__ cont_b,
    const float* __restrict__ clin_w, const float* __restrict__ clin_b,
    const float* __restrict__ fin_bias,
    const float* __restrict__ w1)
{
    __shared__ float lsum[64], lsq[64];

    int tid  = threadIdx.x;
    int lane = tid & 63;
    int wv   = tid >> 6;
    int d    = lane & 31;
    bool lo  = lane < 32;

    if (tid < 64) { lsum[tid] = 0.f; lsq[tid] = 0.f; }
    __syncthreads();

    // W1 row for this lane's h1 output, cat0 column block (cols 0..31)
    float w1c[32];
    {
        const float4* wrv = (const float4*)(w1 + lane * 384);
        #pragma unroll
        for (int q = 0; q < 8; ++q) {
            float4 v = wrv[q];
            w1c[4*q+0] = v.x; w1c[4*q+1] = v.y;
            w1c[4*q+2] = v.z; w1c[4*q+3] = v.w;
        }
    }

    float uk[8];
    #pragma unroll
    for (int j = 0; j < 8; ++j) uk[j] = g_U[j * 64 + lane];
    float vbk = g_Vb[lane];

    float p1[8], p2[8], fb = 0.f;
    if (lo) {
        #pragma unroll
        for (int j = 0; j < 8; ++j) { p1[j] = cont_w[j * 32 + d]; p2[j] = cont_b[j * 32 + d]; }
    } else {
        #pragma unroll
        for (int j = 0; j < 8; ++j) { p1[j] = clin_w[j * 32 + d]; p2[j] = clin_b[j * 32 + d]; }
        fb = fin_bias[d];
    }

    const float* T0 = lo ? emb0 : lin0;
    const float* T1 = lo ? emb1 : lin1;
    const float* T2 = lo ? emb2 : lin2;
    const float* T3 = lo ? emb3 : lin3;

    int gw   = blockIdx.x * 4 + wv;        // 0..12799
    int base = gw * 16;

    float xs[4];
    #pragma unroll
    for (int g = 0; g < 4; ++g)
        xs[g] = (lane < 48) ? x[(base + 4 * g) * 12 + lane] : 0.f;

    float ss = 0.f, qq = 0.f;

    #pragma unroll
    for (int g = 0; g < 4; ++g) {
        // gather the 4-row group (28 independent loads batched before use)
        float ga[4], gb[4], gc[4], gd[4], t1[4], t2[4], t3[4];
        #pragma unroll
        for (int t = 0; t < 4; ++t) {
            int f  = t * 12;
            int i0 = clampi((int)rl_f(xs[g], f + 0), 99999);
            int i1 = clampi((int)rl_f(xs[g], f + 1), 999);
            int i2 = clampi((int)rl_f(xs[g], f + 2), 99);
            int i3 = clampi((int)rl_f(xs[g], f + 3), 49);
            ga[t] = T0[i0 * 32 + d];
            gb[t] = T1[i1 * 32 + d];
            gc[t] = T2[i2 * 32 + d];
            gd[t] = T3[i3 * 32 + d];
            t1[t] = g_E1_1[i1 * 64 + lane];
            t2[t] = g_E1_2[i2 * 64 + lane];
            t3[t] = g_E1_3[i3 * 64 + lane];
        }

        #pragma unroll
        for (int t = 0; t < 4; ++t) {
            int r  = base + 4 * g + t;
            int fo = t * 12 + 4;
            float xc[8];
            #pragma unroll
            for (int j = 0; j < 8; ++j) xc[j] = rl_f(xs[g], fo + j);

            float va = ga[t], vb = gb[t], vc = gc[t], vd = gd[t];

            // inline E1_0: emb0 row lives in lanes 0..31 of va
            float e0a = 0.f, e0b = 0.f, e0c = 0.f, e0d = 0.f;
            #pragma unroll
            for (int dd = 0; dd < 32; dd += 4) {
                e0a = fmaf(rl_f(va, dd + 0), w1c[dd + 0], e0a);
                e0b = fmaf(rl_f(va, dd + 1), w1c[dd + 1], e0b);
                e0c = fmaf(rl_f(va, dd + 2), w1c[dd + 2], e0c);
                e0d = fmaf(rl_f(va, dd + 3), w1c[dd + 3], e0d);
            }
            float e0f = (e0a + e0b) + (e0c + e0d);

            float half_val;
            if (lo) {
                float s0 = va + vb, s1 = vc + vd;
                float q0 = fmaf(va, va, vb * vb);
                float q1 = fmaf(vc, vc, vd * vd);
                #pragma unroll
                for (int j = 0; j < 8; ++j) {
                    float ce = fmaf(xc[j], p1[j], p2[j]);
                    if (j & 1) { s1 += ce; q1 = fmaf(ce, ce, q1); }
                    else       { s0 += ce; q0 = fmaf(ce, ce, q0); }
                }
                float sfull = s0 + s1;
                half_val = 0.5f * (sfull * sfull - (q0 + q1));   // interaction
            } else {
                float l0 = va + vb + fb, l1 = vc + vd;
                #pragma unroll
                for (int j = 0; j < 8; ++j) {
                    if (j & 1) l1 = fmaf(xc[j], p1[j], l1 + p2[j]);
                    else       l0 = fmaf(xc[j], p1[j], l0 + p2[j]);
                }
                half_val = l0 + l1;                              // linear
            }
            float other = __shfl(half_val, lane | 32);
            if (lo) g_fmp[r * 32 + d] = __float2bfloat16(half_val + other);

            float h1 = ((vbk + e0f) + (t1[t] + t2[t])) + t3[t];
            #pragma unroll
            for (int j = 0; j < 8; ++j) h1 = fmaf(xc[j], uk[j], h1);

            g_h1p[r * 64 + lane] = __float2bfloat16(h1);
            ss += h1;
            qq = fmaf(h1, h1, qq);
        }
    }

    atomicAdd(&lsum[lane], ss);
    atomicAdd(&lsq[lane], qq);
    __syncthreads();
    if (tid < 64) {
        atomicAdd(&g_stats[tid], lsum[tid]);        // sum1
        atomicAdd(&g_stats[64 + tid], lsq[tid]);    // sumsq1
    }
}

// ---------------------------------------------------------------------------
// Phase 2 (row-per-lane, LDS-staged; unchanged).
// ---------------------------------------------------------------------------
__global__ __launch_bounds__(256) void phase2_kernel(
    const float* __restrict__ w2, const float* __restrict__ b2,
    const float* __restrict__ g1, const float* __restrict__ beta1)
{
    __shared__ float sa[64], sc[64];
    __shared__ float ls[64];                 // ls[m]=sum2, ls[32+m]=sumsq2
    __shared__ uint4 hbuf[4][512];           // 4 waves x 8 KB (wave-private)

    int tid  = threadIdx.x;
    int lane = tid & 63;
    int wv   = tid >> 6;
    size_t rowBase = (size_t)(blockIdx.x * 4 + wv) * 64;

    {
        const char* gsrc = (const char*)g_h1p + rowBase * 128;
        #pragma unroll
        for (int i = 0; i < 8; ++i) {
            int dlin = (i << 6) + lane;
            GLOAD16(gsrc + swz8(dlin) * 16, &hbuf[wv][i << 6]);
        }
    }

    if (tid < 64) {
        float mu  = g_stats[tid] * N_INV;
        float var = g_stats[64 + tid] * N_INV - mu * mu;
        float a   = g1[tid] * rsqrtf(var + 1e-5f);
        sa[tid] = a;
        sc[tid] = beta1[tid] - a * mu;
        ls[tid] = 0.f;
    }
    __syncthreads();
    asm volatile("s_waitcnt vmcnt(0)" ::: "memory");

    const uint4* lrow = hbuf[wv] + (lane << 3);
    int r7 = lane & 7;

    float acc[32];
    #pragma unroll
    for (int m = 0; m < 32; ++m) acc[m] = 0.f;

    #pragma unroll
    for (int half = 0; half < 2; ++half) {
        uint4 u[4];
        #pragma unroll
        for (int q = 0; q < 4; ++q) u[q] = lrow[(half * 4 + q) ^ r7];

        float y[32];
        #pragma unroll
        for (int q = 0; q < 4; ++q) {
            unsigned int w4[4] = {u[q].x, u[q].y, u[q].z, u[q].w};
            #pragma unroll
            for (int j = 0; j < 4; ++j) {
                int i  = q * 4 + j;
                int ch = half * 32 + 2 * i;
                float f0 = __uint_as_float(w4[j] << 16);
                float f1 = __uint_as_float(w4[j] & 0xffff0000u);
                y[2*i]     = fmaxf(0.f, fmaf(sa[ch],     f0, sc[ch]));
                y[2*i + 1] = fmaxf(0.f, fmaf(sa[ch + 1], f1, sc[ch + 1]));
            }
        }

        #pragma unroll
        for (int m = 0; m < 32; ++m) {
            const float* wr = w2 + m * 64 + half * 32;   // uniform -> scalar
            float a0 = 0.f, a1 = 0.f, a2 = 0.f, a3 = 0.f;
            #pragma unroll
            for (int k = 0; k < 32; k += 4) {
                a0 = fmaf(y[k + 0], wr[k + 0], a0);
                a1 = fmaf(y[k + 1], wr[k + 1], a1);
                a2 = fmaf(y[k + 2], wr[k + 2], a2);
                a3 = fmaf(y[k + 3], wr[k + 3], a3);
            }
            acc[m] += (a0 + a1) + (a2 + a3);
        }
    }

    #pragma unroll
    for (int m = 0; m < 32; ++m) acc[m] += b2[m];

    uint4 o[4];
    unsigned int* ow = (unsigned int*)o;
    #pragma unroll
    for (int i = 0; i < 16; ++i) {
        unsigned int lo16 = (unsigned int)__bfloat16_as_ushort(__float2bfloat16(acc[2*i]));
        unsigned int hi16 = (unsigned int)__bfloat16_as_ushort(__float2bfloat16(acc[2*i + 1]));
        ow[i] = lo16 | (hi16 << 16);
    }

    #pragma unroll
    for (int q = 0; q < 4; ++q) hbuf[wv][swz4((lane << 2) + q)] = o[q];
    asm volatile("s_waitcnt lgkmcnt(0)" ::: "memory");
    {
        uint4* og = (uint4*)(g_h2p + rowBase * 32);
        #pragma unroll
        for (int i = 0; i < 4; ++i) {
            int dlin = (i << 6) + lane;
            og[dlin] = hbuf[wv][swz4(dlin)];
        }
    }

    #pragma unroll
    for (int c0 = 0; c0 < 32; c0 += 8) {
        float s[8], q[8];
        #pragma unroll
        for (int j = 0; j < 8; ++j) { s[j] = acc[c0 + j]; q[j] = s[j] * s[j]; }
        #pragma unroll
        for (int off = 32; off >= 1; off >>= 1) {
            #pragma unroll
            for (int j = 0; j < 8; ++j) {
                s[j] += __shfl_xor(s[j], off);
                q[j] += __shfl_xor(q[j], off);
            }
        }
        if (lane == 0) {
            #pragma unroll
            for (int j = 0; j < 8; ++j) {
                atomicAdd(&ls[c0 + j],      s[j]);
                atomicAdd(&ls[32 + c0 + j], q[j]);
            }
        }
    }
    __syncthreads();
    if (tid < 32)       atomicAdd(&g_stats[128 + tid], ls[tid]);
    else if (tid < 64)  atomicAdd(&g_stats[160 + (tid - 32)], ls[tid]);
}

// ---------------------------------------------------------------------------
// Phase 3 (row-per-lane, LDS-staged; unchanged).
// ---------------------------------------------------------------------------
__global__ __launch_bounds__(256) void phase3_kernel(
    const float* __restrict__ w_out, const float* __restrict__ b_out,
    const float* __restrict__ g2, const float* __restrict__ beta2,
    float* __restrict__ out)
{
    __shared__ float sa[32], sc[32];
    __shared__ uint4 sbuf[4][512];           // per wave: [0,256)=h2, [256,512)=fm

    int tid  = threadIdx.x;
    int lane = tid & 63;
    int wv   = tid >> 6;
    size_t rowBase = (size_t)(blockIdx.x * 4 + wv) * 64;

    {
        const char* gh2 = (const char*)g_h2p + rowBase * 64;
        const char* gfm = (const char*)g_fmp + rowBase * 64;
        #pragma unroll
        for (int i = 0; i < 4; ++i) {
            int dlin = (i << 6) + lane;
            GLOAD16(gh2 + swz4(dlin) * 16, &sbuf[wv][i << 6]);
        }
        #pragma unroll
        for (int i = 0; i < 4; ++i) {
            int dlin = (i << 6) + lane;
            GLOAD16(gfm + swz4(dlin) * 16, &sbuf[wv][256 + (i << 6)]);
        }
    }

    if (tid < 32) {
        float mu  = g_stats[128 + tid] * N_INV;
        float var = g_stats[160 + tid] * N_INV - mu * mu;
        float a   = g2[tid] * rsqrtf(var + 1e-5f);
        sa[tid] = a;
        sc[tid] = beta2[tid] - a * mu;
    }
    __syncthreads();
    asm volatile("s_waitcnt vmcnt(0)" ::: "memory");

    uint4 u[4], fm4[4];
    #pragma unroll
    for (int q = 0; q < 4; ++q) {
        int gidx = swz4((lane << 2) + q);
        u[q]   = sbuf[wv][gidx];
        fm4[q] = sbuf[wv][256 + gidx];
    }

    float y2[32];
    #pragma unroll
    for (int q = 0; q < 4; ++q) {
        unsigned int w4[4] = {u[q].x, u[q].y, u[q].z, u[q].w};
        #pragma unroll
        for (int j = 0; j < 4; ++j) {
            int i = q * 4 + j;
            float f0 = __uint_as_float(w4[j] << 16);
            float f1 = __uint_as_float(w4[j] & 0xffff0000u);
            y2[2*i]     = fmaxf(0.f, fmaf(sa[2*i],     f0, sc[2*i]));
            y2[2*i + 1] = fmaxf(0.f, fmaf(sa[2*i + 1], f1, sc[2*i + 1]));
        }
    }

    float fmv[32];
    {
        const unsigned int* fw = (const unsigned int*)fm4;
        #pragma unroll
        for (int i = 0; i < 16; ++i) {
            fmv[2*i]     = __uint_as_float(fw[i] << 16);
            fmv[2*i + 1] = __uint_as_float(fw[i] & 0xffff0000u);
        }
    }

    float res[32];
    #pragma unroll
    for (int dd = 0; dd < 32; ++dd) {
        const float* wr = w_out + dd * 32;           // uniform -> scalar
        float a0 = fmv[dd] + b_out[dd], a1 = 0.f, a2 = 0.f, a3 = 0.f;
        #pragma unroll
        for (int k = 0; k < 32; k += 4) {
            a0 = fmaf(y2[k + 0], wr[k + 0], a0);
            a1 = fmaf(y2[k + 1], wr[k + 1], a1);
            a2 = fmaf(y2[k + 2], wr[k + 2], a2);
            a3 = fmaf(y2[k + 3], wr[k + 3], a3);
        }
        res[dd] = (a0 + a1) + (a2 + a3);
    }

    #pragma unroll
    for (int q = 0; q < 8; ++q) {
        uint4 v;
        v.x = __float_as_uint(res[4*q+0]);
        v.y = __float_as_uint(res[4*q+1]);
        v.z = __float_as_uint(res[4*q+2]);
        v.w = __float_as_uint(res[4*q+3]);
        sbuf[wv][swz8((lane << 3) + q)] = v;
    }
    asm volatile("s_waitcnt lgkmcnt(0)" ::: "memory");
    {
        uint4* og = (uint4*)(out + rowBase * 32);
        #pragma unroll
        for (int i = 0; i < 8; ++i) {
            int dlin = (i << 6) + lane;
            og[dlin] = sbuf[wv][swz8(dlin)];
        }
    }
}

// ---------------------------------------------------------------------------
extern "C" void kernel_launch(void* const* d_in, const int* in_sizes, int n_in,
                              void* d_out, int out_size, void* d_ws, size_t ws_size,
                              hipStream_t stream) {
    (void)in_sizes; (void)n_in; (void)out_size; (void)d_ws; (void)ws_size;

    // setup_inputs() dict order (emb/lin interleaved!) — all float32
    const float* x       = (const float*)d_in[0];
    const float* emb0    = (const float*)d_in[1];
    const float* lin0    = (const float*)d_in[2];
    const float* emb1    = (const float*)d_in[3];
    const float* lin1    = (const float*)d_in[4];
    const float* emb2    = (const float*)d_in[5];
    const float* lin2    = (const float*)d_in[6];
    const float* emb3    = (const float*)d_in[7];
    const float* lin3    = (const float*)d_in[8];
    const float* cont_w  = (const float*)d_in[9];
    const float* cont_b  = (const float*)d_in[10];
    const float* clin_w  = (const float*)d_in[11];
    const float* clin_b  = (const float*)d_in[12];
    const float* fin_bias= (const float*)d_in[13];
    const float* w1      = (const float*)d_in[14];
    const float* b1      = (const float*)d_in[15];
    const float* g1      = (const float*)d_in[16];
    const float* beta1   = (const float*)d_in[17];
    const float* w2      = (const float*)d_in[18];
    const float* b2      = (const float*)d_in[19];
    const float* g2      = (const float*)d_in[20];
    const float* beta2   = (const float*)d_in[21];
    const float* w_out   = (const float*)d_in[22];
    const float* b_out   = (const float*)d_in[23];

    float* outp = (float*)d_out;

    hipLaunchKernelGGL(precompute_kernel, dim3(1151), dim3(64), 0, stream,
                       emb1, emb2, emb3, cont_w, cont_b, w1, b1);

    hipLaunchKernelGGL(phase1_kernel, dim3(3200), dim3(256), 0, stream,
                       x, emb0, lin0, emb1, lin1, emb2, lin2, emb3, lin3,
                       cont_w, cont_b, clin_w, clin_b, fin_bias, w1);

    hipLaunchKernelGGL(phase2_kernel, dim3(800), dim3(256), 0, stream,
                       w2, b2, g1, beta1);

    hipLaunchKernelGGL(phase3_kernel, dim3(800), dim3(256), 0, stream,
                       w_out, b_out, g2, beta2, outp);
}